// Round 21
// baseline (140.282 us; speedup 1.0000x reference)
//
#include <hip/hip_runtime.h>
#include <hip/hip_bf16.h>

#define NNODES 131072
#define NEDGES 2097152
#define BSUB   1024
#define SSUB   128
#define FIN    300
#define FOUT   64
#define NCHUNK 256
#define CHEDGE 8192

typedef __attribute__((ext_vector_type(8))) short short8;
typedef __attribute__((ext_vector_type(8))) unsigned short ushort8;
typedef __attribute__((ext_vector_type(4))) float f32x4;

// hardware RNE f32->bf16 (compiler lowers pairs to v_cvt_pk_bf16_f32)
__device__ inline unsigned short f2bfbits(float f) {
    union { __hip_bfloat16 h; unsigned short u; } cv;
    cv.h = __float2bfloat16(f);
    return cv.u;
}
__device__ inline float bf2f(unsigned short b) {
    return __uint_as_float(((unsigned)b) << 16);
}
__device__ inline void gload_lds16(const float* g, void* l) {
    __builtin_amdgcn_global_load_lds(
        (const __attribute__((address_space(1))) unsigned int*)g,
        (__attribute__((address_space(3))) unsigned int*)l,
        16, 0, 0);
}

// ---------------------------------------------------------------------------
// Dispatch 1: per-chunk LDS counting-sort (R13/R20 body, unchanged).
// ---------------------------------------------------------------------------
__global__ __launch_bounds__(256) void bucket_kernel(const int* __restrict__ src,
                                                     const int* __restrict__ dst,
                                                     unsigned* __restrict__ ofs,
                                                     unsigned short* __restrict__ bkt) {
    __shared__ unsigned short epack[CHEDGE];    // 16 KB
    __shared__ unsigned short eg[CHEDGE];       // 16 KB
    __shared__ unsigned short sorted[CHEDGE];   // 16 KB
    __shared__ int hist[BSUB];                  // 4 KB
    __shared__ int cur[BSUB];                   // 4 KB
    __shared__ int wsum[4];

    const int cb = blockIdx.x;
    const int t = threadIdx.x;
    for (int i = t; i < BSUB; i += 256) hist[i] = 0;
    __syncthreads();

    const int4* sp = (const int4*)(src + (size_t)cb * CHEDGE);
    const int4* dp = (const int4*)(dst + (size_t)cb * CHEDGE);
    for (int i = t; i < CHEDGE / 4; i += 256) {
        int4 s4 = sp[i], d4 = dp[i];
#pragma unroll
        for (int k = 0; k < 4; ++k) {
            int s = (k == 0) ? s4.x : (k == 1) ? s4.y : (k == 2) ? s4.z : s4.w;
            int d = (k == 0) ? d4.x : (k == 1) ? d4.y : (k == 2) ? d4.z : d4.w;
            int g = s >> 7;
            epack[i * 4 + k] = (unsigned short)(((s & 127) << 7) | (d & 127));
            eg[i * 4 + k] = (unsigned short)g;
            atomicAdd(&hist[g], 1);
        }
    }
    __syncthreads();

    {   // block exclusive scan over 1024 bins (thread t owns bins 4t..4t+3)
        int lane = t & 63, w = t >> 6;
        int c0 = hist[4 * t], c1 = hist[4 * t + 1], c2 = hist[4 * t + 2], c3 = hist[4 * t + 3];
        int s = c0 + c1 + c2 + c3;
        int pre = s;
#pragma unroll
        for (int o = 1; o < 64; o <<= 1) {
            int v = __shfl_up(pre, o, 64);
            if (lane >= o) pre += v;
        }
        if (lane == 63) wsum[w] = pre;
        __syncthreads();
        int wbase = 0;
        for (int i = 0; i < w; ++i) wbase += wsum[i];
        int excl = wbase + pre - s;
        uint4 ov;
        ov.x = ((unsigned)excl << 16) | (unsigned)c0; cur[4 * t]     = excl; excl += c0;
        ov.y = ((unsigned)excl << 16) | (unsigned)c1; cur[4 * t + 1] = excl; excl += c1;
        ov.z = ((unsigned)excl << 16) | (unsigned)c2; cur[4 * t + 2] = excl; excl += c2;
        ov.w = ((unsigned)excl << 16) | (unsigned)c3; cur[4 * t + 3] = excl;
        ((uint4*)(ofs + (size_t)cb * BSUB))[t] = ov;       // coalesced 16B/thread
    }
    __syncthreads();

    for (int i = t; i < CHEDGE; i += 256) {     // LDS scatter
        int g = eg[i];
        int r = atomicAdd(&cur[g], 1);
        sorted[r] = epack[i];
    }
    __syncthreads();

    {   // coalesced streaming writeout (16 KB contiguous)
        ushort8* outv = (ushort8*)(bkt + (size_t)cb * CHEDGE);
        const ushort8* sv = (const ushort8*)sorted;
        for (int i = t; i < CHEDGE / 8; i += 256) outv[i] = sv[i];
    }
}

// ---------------------------------------------------------------------------
// Dispatch 2: FUSED per-subgraph gemm + aggregate + norm + PReLU + pool.
// Block g owns subgraph g (128 rows). All components individually verified:
//  - B-fragments direct from W (R17, passed), RNE-identical to wfrag path
//  - 64-row halves staged via global_load_lds, swizzled src (R12, passed)
//  - register K-tail k[256,300) with kgrp predication (R9, passed)
//  - MFMA D-fragments written STRAIGHT to the hl LDS tile (no hb global
//    round-trip: -32 MB traffic, -1 dispatch vs R20)
//  - R13 agg body reading hl from LDS (passed)
// LDS 59 KB -> 2 blocks/CU so per-block phase barriers overlap across blocks.
// ---------------------------------------------------------------------------
__global__ __launch_bounds__(256, 2) void fused_kernel(const float* __restrict__ x,
                                                       const float* __restrict__ W,
                                                       const unsigned short* __restrict__ bkt,
                                                       const unsigned* __restrict__ ofs,
                                                       const float* __restrict__ bias,
                                                       const float* __restrict__ prelu,
                                                       float* __restrict__ out) {
    __shared__ __align__(16) char smem[59904];
    char*           buf  = smem;                              // 32 KB staging
    unsigned short* hl   = (unsigned short*)(smem + 32768);   // 16 KB [128][64]
    unsigned char*  es   = (unsigned char*)(smem + 49152);    // 8 KB [128][64]
    int*            din  = (int*)(smem + 57344);              // 512 B
    int*            dout = (int*)(smem + 57856);              // 512 B
    float*          rout = (float*)(smem + 58368);            // 512 B
    float*          ps   = (float*)(smem + 58880);            // 1 KB

    const int g = blockIdx.x;
    const int t = threadIdx.x;
    const int lane = t & 63;
    const int wave = t >> 6;        // = ct (col tile)
    const int kg = lane >> 4;

    // --- B preload direct from W (L2-hot 75 KB; R17-verified) ---
    short8 bq[10];
    {
        const int colW = wave * 16 + (lane & 15);
        const int krow = kg * 8;
#pragma unroll
        for (int kt = 0; kt < 10; ++kt) {
#pragma unroll
            for (int e = 0; e < 8; ++e) {
                int k = kt * 32 + krow + e;
                float v = (k < FIN) ? W[(size_t)k * FOUT + colW] : 0.f;
                bq[kt][e] = (short)f2bfbits(v);
            }
        }
    }
    if (t < SSUB) { din[t] = 0; dout[t] = 0; }   // visible after first barrier

    // --- GEMM: two 64-row halves, single 32 KB buffer re-staged ---
#pragma unroll
    for (int half = 0; half < 2; ++half) {
        const int rowbase = g * SSUB + half * 64;

        // register K-tail (R9-verified predication; k>=300 hits zero B rows)
        f32x4 t8l[4], t8h[4], t9l[4], t9h[4];
#pragma unroll
        for (int rt = 0; rt < 4; ++rt) {
            const float* arp = x + (size_t)(rowbase + rt * 16 + (lane & 15)) * FIN;
            t8l[rt] = *(const f32x4*)(arp + 256 + kg * 8);   // k 256..287: all valid
            t8h[rt] = *(const f32x4*)(arp + 256 + kg * 8 + 4);
            t9l[rt] = (f32x4){0.f, 0.f, 0.f, 0.f};
            t9h[rt] = (f32x4){0.f, 0.f, 0.f, 0.f};
            if (kg == 0) {
                t9l[rt] = *(const f32x4*)(arp + 288);
                t9h[rt] = *(const f32x4*)(arp + 292);
            } else if (kg == 1) {
                t9l[rt] = *(const f32x4*)(arp + 296);
            }
        }

        // stage k[0,128) -> buf (swizzled source, linear dest)
#pragma unroll
        for (int i = wave; i < 32; i += 4) {
            int o = i * 1024 + lane * 16;
            int row = o >> 9;
            int c = o & 511;
            int csrc = c ^ ((row & 7) << 4);
            gload_lds16(x + (size_t)(rowbase + row) * FIN + (csrc >> 2), buf + i * 1024);
        }

        f32x4 acc[4];
#pragma unroll
        for (int r = 0; r < 4; ++r) acc[r] = (f32x4){0.f, 0.f, 0.f, 0.f};

        __syncthreads();        // drain stage-1 DMA (also orders prev-half hl writes)

        // MFMA kt 0..3 from buf
#pragma unroll
        for (int rt = 0; rt < 4; ++rt) {
            const int rl = rt * 16 + (lane & 15);
            const int sw = (rl & 7) << 4;
#pragma unroll
            for (int kt = 0; kt < 4; ++kt) {
                int c0 = kt * 128 + kg * 32;
                f32x4 lo = *(const f32x4*)(buf + rl * 512 + (c0 ^ sw));
                f32x4 hi = *(const f32x4*)(buf + rl * 512 + ((c0 + 16) ^ sw));
                short8 afr;
                afr[0] = (short)f2bfbits(lo[0]); afr[1] = (short)f2bfbits(lo[1]);
                afr[2] = (short)f2bfbits(lo[2]); afr[3] = (short)f2bfbits(lo[3]);
                afr[4] = (short)f2bfbits(hi[0]); afr[5] = (short)f2bfbits(hi[1]);
                afr[6] = (short)f2bfbits(hi[2]); afr[7] = (short)f2bfbits(hi[3]);
                acc[rt] = __builtin_amdgcn_mfma_f32_16x16x32_bf16(afr, bq[kt], acc[rt], 0, 0, 0);
            }
        }
        __syncthreads();        // all waves done reading buf (stage-1 data)

        // stage k[128,256) -> buf
#pragma unroll
        for (int i = wave; i < 32; i += 4) {
            int o = i * 1024 + lane * 16;
            int row = o >> 9;
            int c = o & 511;
            int csrc = c ^ ((row & 7) << 4);
            gload_lds16(x + (size_t)(rowbase + row) * FIN + 128 + (csrc >> 2), buf + i * 1024);
        }
        __syncthreads();        // drain stage-2 DMA

        // MFMA kt 4..7 from buf, kt 8..9 from registers; write hl
#pragma unroll
        for (int rt = 0; rt < 4; ++rt) {
            const int rl = rt * 16 + (lane & 15);
            const int sw = (rl & 7) << 4;
#pragma unroll
            for (int kt = 4; kt < 10; ++kt) {
                f32x4 lo, hi;
                if (kt < 8) {
                    int c0 = (kt - 4) * 128 + kg * 32;
                    lo = *(const f32x4*)(buf + rl * 512 + (c0 ^ sw));
                    hi = *(const f32x4*)(buf + rl * 512 + ((c0 + 16) ^ sw));
                } else if (kt == 8) {
                    lo = t8l[rt]; hi = t8h[rt];
                } else {
                    lo = t9l[rt]; hi = t9h[rt];
                }
                short8 afr;
                afr[0] = (short)f2bfbits(lo[0]); afr[1] = (short)f2bfbits(lo[1]);
                afr[2] = (short)f2bfbits(lo[2]); afr[3] = (short)f2bfbits(lo[3]);
                afr[4] = (short)f2bfbits(hi[0]); afr[5] = (short)f2bfbits(hi[1]);
                afr[6] = (short)f2bfbits(hi[2]); afr[7] = (short)f2bfbits(hi[3]);
                acc[rt] = __builtin_amdgcn_mfma_f32_16x16x32_bf16(afr, bq[kt], acc[rt], 0, 0, 0);
            }
            // D layout: row = rt*16 + (lane>>4)*4 + r, col = wave*16 + (lane&15)
            const int colb = wave * 16 + (lane & 15);
            const int rbase = half * 64 + rt * 16 + (lane >> 4) * 4;
#pragma unroll
            for (int r = 0; r < 4; ++r)
                hl[(rbase + r) * FOUT + colb] = f2bfbits(acc[rt][r]);
        }
        __syncthreads();        // buf reads + hl writes done before next half
    }

    // --- edge pass (R13 agg body): thread t consumes chunk t's run ---
    {
        unsigned w32 = ofs[(size_t)t * BSUB + g];
        int st = (int)(w32 >> 16), cn = (int)(w32 & 0xffff);
        const unsigned short* ebb = bkt + ((size_t)t << 13) + st;
        for (int i = 0; i < cn; ++i) {
            unsigned e = ebb[i];
            int s = e >> 7, d = e & 127;
            int r = atomicAdd(&din[d], 1);
            es[d * 64 + (r & 63)] = (unsigned char)s;
            atomicAdd(&dout[s], 1);
        }
    }
    __syncthreads();
    if (t < SSUB) rout[t] = rsqrtf((float)max(dout[t], 1));
    __syncthreads();

    // --- register aggregation: wave w owns dst rows w, w+4, ... ---
    const float bv = bias[lane];
    const float a = prelu[0];
    float pool = 0.f;
#pragma unroll 4
    for (int ii = 0; ii < 32; ++ii) {
        int d = wave + 4 * ii;
        int cd = min(din[d], 64);
        float accv = 0.f;
        const unsigned* ew = (const unsigned*)&es[d * 64];
        int nw = (cd + 3) >> 2;
        for (int p = 0; p < nw; ++p) {
            unsigned wd = ew[p];                        // broadcast LDS read
            int rem = cd - p * 4;
#pragma unroll
            for (int b = 0; b < 4; ++b) {
                if (b < rem) {                          // wave-uniform predicate
                    int s = (wd >> (8 * b)) & 127;
                    accv += bf2f(hl[s * FOUT + lane]) * rout[s];
                }
            }
        }
        float v = accv * rsqrtf((float)max(din[d], 1)) + bv;
        v = (v > 0.f) ? v : a * v;
        if (d == SSUB - 1)
            out[(size_t)(BSUB + g) * FOUT + lane] = v;  // anchor (wave 3)
        else
            pool += v;
    }
    ps[wave * 64 + lane] = pool;
    __syncthreads();
    if (wave == 0) {
        float s = (ps[lane] + ps[64 + lane]) + (ps[128 + lane] + ps[192 + lane]);
        out[(size_t)g * FOUT + lane] = s * (1.0f / 127.0f);
    }
}

// ---------------------------------------------------------------------------
extern "C" void kernel_launch(void* const* d_in, const int* in_sizes, int n_in,
                              void* d_out, int out_size, void* d_ws, size_t ws_size,
                              hipStream_t stream) {
    const float* in_feat = (const float*)d_in[0];
    const float* W       = (const float*)d_in[1];
    const float* bias    = (const float*)d_in[2];
    const float* prelu   = (const float*)d_in[3];
    const int*   src     = (const int*)d_in[4];
    const int*   dst     = (const int*)d_in[5];
    float* out = (float*)d_out;

    char* ws = (char*)d_ws;
    unsigned*       ofs = (unsigned*)(ws + (2u << 20));        // 1 MB (256x1024 u32)
    unsigned short* bkt = (unsigned short*)(ws + (4u << 20));  // 4 MB (256x8192 u16)

    hipLaunchKernelGGL(bucket_kernel, dim3(NCHUNK), dim3(256), 0, stream,
                       src, dst, ofs, bkt);
    hipLaunchKernelGGL(fused_kernel,  dim3(BSUB),   dim3(256), 0, stream,
                       in_feat, W, bkt, ofs, bias, prelu, out);
}

// Round 22
// 102.766 us; speedup vs baseline: 1.3651x; 1.3651x over previous
//
#include <hip/hip_runtime.h>
#include <hip/hip_bf16.h>

#define NNODES 131072
#define NEDGES 2097152
#define BSUB   1024
#define SSUB   128
#define FIN    300
#define FOUT   64
#define NCHUNK 256
#define CHEDGE 8192

typedef __attribute__((ext_vector_type(8))) short short8;
typedef __attribute__((ext_vector_type(8))) unsigned short ushort8;
typedef __attribute__((ext_vector_type(4))) float f32x4;

// hardware RNE f32->bf16 (compiler lowers pairs to v_cvt_pk_bf16_f32)
__device__ inline unsigned short f2bfbits(float f) {
    union { __hip_bfloat16 h; unsigned short u; } cv;
    cv.h = __float2bfloat16(f);
    return cv.u;
}
__device__ inline float bf2f(unsigned short b) {
    return __uint_as_float(((unsigned)b) << 16);
}
__device__ inline void gload_lds16(const float* g, void* l) {
    __builtin_amdgcn_global_load_lds(
        (const __attribute__((address_space(1))) unsigned int*)g,
        (__attribute__((address_space(3))) unsigned int*)l,
        16, 0, 0);
}

// ---------------------------------------------------------------------------
// R22 = R20 exactly (best measured: 103.1 us). R21's gemm+agg fusion
// regressed to 183 us (3rd fusion failure: unlike phases serialize behind
// shared barriers at reduced occupancy). This is the terminal configuration:
//  - bucket+prep hetero kernel (10 trivial prep blocks; the only merge that
//    works because prep is not a role-split, just tail blocks)
//  - gemm at the HBM floor (23 us for the 157 MB in_feat read, calibrated
//    via R12's duplicate-launch delta; ~6.8 TB/s)
//  - agg_pool (insensitive to rewrites: R15 null)
// Remaining ~45 us = fixed replay/dispatch overhead outside kernel control.
// ---------------------------------------------------------------------------
__global__ __launch_bounds__(256) void bucket_prep_kernel(const int* __restrict__ src,
                                                          const int* __restrict__ dst,
                                                          unsigned* __restrict__ ofs,
                                                          unsigned short* __restrict__ bkt,
                                                          const float* __restrict__ W,
                                                          short* __restrict__ wfrag) {
    __shared__ unsigned short epack[CHEDGE];    // 16 KB
    __shared__ unsigned short eg[CHEDGE];       // 16 KB
    __shared__ unsigned short sorted[CHEDGE];   // 16 KB
    __shared__ int hist[BSUB];                  // 4 KB
    __shared__ int cur[BSUB];                   // 4 KB
    __shared__ int wsum[4];

    if (blockIdx.x >= NCHUNK) {
        // ---- prep_w role (blocks 256..265; 2560 fragment-units total) ----
        int idx = (blockIdx.x - NCHUNK) * 256 + threadIdx.x;
        if (idx < 2560) {
            int ct   = idx / 640;
            int rem  = idx % 640;
            int kt   = rem / 64;
            int lane = rem % 64;
            int col  = ct * 16 + (lane & 15);
            int kb   = kt * 32 + (lane >> 4) * 8;
#pragma unroll
            for (int e = 0; e < 8; ++e) {
                int k = kb + e;
                float v = (k < FIN) ? W[(size_t)k * FOUT + col] : 0.f;
                wfrag[(size_t)idx * 8 + e] = (short)f2bfbits(v);
            }
        }
        return;
    }

    // ---- bucket role (counting-sort) ----
    const int cb = blockIdx.x;
    const int t = threadIdx.x;
    for (int i = t; i < BSUB; i += 256) hist[i] = 0;
    __syncthreads();

    const int4* sp = (const int4*)(src + (size_t)cb * CHEDGE);
    const int4* dp = (const int4*)(dst + (size_t)cb * CHEDGE);
    for (int i = t; i < CHEDGE / 4; i += 256) {
        int4 s4 = sp[i], d4 = dp[i];
#pragma unroll
        for (int k = 0; k < 4; ++k) {
            int s = (k == 0) ? s4.x : (k == 1) ? s4.y : (k == 2) ? s4.z : s4.w;
            int d = (k == 0) ? d4.x : (k == 1) ? d4.y : (k == 2) ? d4.z : d4.w;
            int g = s >> 7;
            epack[i * 4 + k] = (unsigned short)(((s & 127) << 7) | (d & 127));
            eg[i * 4 + k] = (unsigned short)g;
            atomicAdd(&hist[g], 1);
        }
    }
    __syncthreads();

    {   // block exclusive scan over 1024 bins (thread t owns bins 4t..4t+3)
        int lane = t & 63, w = t >> 6;
        int c0 = hist[4 * t], c1 = hist[4 * t + 1], c2 = hist[4 * t + 2], c3 = hist[4 * t + 3];
        int s = c0 + c1 + c2 + c3;
        int pre = s;
#pragma unroll
        for (int o = 1; o < 64; o <<= 1) {
            int v = __shfl_up(pre, o, 64);
            if (lane >= o) pre += v;
        }
        if (lane == 63) wsum[w] = pre;
        __syncthreads();
        int wbase = 0;
        for (int i = 0; i < w; ++i) wbase += wsum[i];
        int excl = wbase + pre - s;
        uint4 ov;
        ov.x = ((unsigned)excl << 16) | (unsigned)c0; cur[4 * t]     = excl; excl += c0;
        ov.y = ((unsigned)excl << 16) | (unsigned)c1; cur[4 * t + 1] = excl; excl += c1;
        ov.z = ((unsigned)excl << 16) | (unsigned)c2; cur[4 * t + 2] = excl; excl += c2;
        ov.w = ((unsigned)excl << 16) | (unsigned)c3; cur[4 * t + 3] = excl;
        ((uint4*)(ofs + (size_t)cb * BSUB))[t] = ov;       // coalesced 16B/thread
    }
    __syncthreads();

    // LDS scatter (int atomics on cur, LDS-speed)
    for (int i = t; i < CHEDGE; i += 256) {
        int g = eg[i];
        int r = atomicAdd(&cur[g], 1);
        sorted[r] = epack[i];
    }
    __syncthreads();

    // coalesced streaming writeout (16 KB contiguous)
    {
        ushort8* outv = (ushort8*)(bkt + (size_t)cb * CHEDGE);
        const ushort8* sv = (const ushort8*)sorted;
        for (int i = t; i < CHEDGE / 8; i += 256) outv[i] = sv[i];
    }
}

// ---------------------------------------------------------------------------
// h = in_feat @ W, bf16 MFMA 16x16x32 (R12/R13 structure, ~23 us == HBM
// floor for the 157 MB read, established by the R12 duplicate-launch delta).
// ---------------------------------------------------------------------------
__global__ __launch_bounds__(256, 2) void gemm_kernel(const float* __restrict__ x,
                                                      const short* __restrict__ wfrag,
                                                      unsigned short* __restrict__ hb) {
    __shared__ __align__(16) char smem[77824];      // 32K bufA + 32K bufB + 12K aux
    char* bufA = smem;                  // k[0,128)   rows of 512 B (swizzled)
    char* bufB = smem + 32768;          // k[128,256) rows of 512 B (swizzled)
    char* aux  = smem + 65536;          // tail k[256,300) rows of 176 B; then st

    const int wave = threadIdx.x >> 6;          // = ct (col tile)
    const int lane = threadIdx.x & 63;
    const int rowbase = blockIdx.x * 64;

    // B preload: this wave's 10 fragments -> 40 VGPRs (coalesced 16B)
    short8 bq[10];
#pragma unroll
    for (int kt = 0; kt < 10; ++kt)
        bq[kt] = *(const short8*)(wfrag + ((size_t)(wave * 10 + kt) * 64 + lane) * 8);

    // A staging DMA: contiguous, source pre-swizzled
#pragma unroll
    for (int i = wave; i < 32; i += 4) {
        int o = i * 1024 + lane * 16;
        int row = o >> 9;
        int c = o & 511;
        int csrc = c ^ ((row & 7) << 4);
        gload_lds16(x + (size_t)(rowbase + row) * FIN + (csrc >> 2), bufA + i * 1024);
    }
#pragma unroll
    for (int i = wave; i < 32; i += 4) {
        int o = i * 1024 + lane * 16;
        int row = o >> 9;
        int c = o & 511;
        int csrc = c ^ ((row & 7) << 4);
        gload_lds16(x + (size_t)(rowbase + row) * FIN + 128 + (csrc >> 2), bufB + i * 1024);
    }
    // tail k[256,300): 176 B/row, 64 rows = 11264 B into aux (11 insts)
    for (int i = wave; i < 11; i += 4) {
        int o = i * 1024 + lane * 16;
        int row = o / 176;
        int c = o - row * 176;
        gload_lds16(x + (size_t)(rowbase + row) * FIN + 256 + (c >> 2), aux + i * 1024);
    }
    // zero the aux slack [11264, 12288): kt=9 over-read lands here.
    ((float*)(aux + 11264))[threadIdx.x] = 0.f;

    f32x4 acc[4];
#pragma unroll
    for (int r = 0; r < 4; ++r) acc[r] = (f32x4){0.f, 0.f, 0.f, 0.f};

    const int kg = lane >> 4;

    __syncthreads();    // drains ALL DMA; publishes bufA/bufB/aux

    // MFMA loop: rt x kt, pure LDS + registers
#pragma unroll
    for (int rt = 0; rt < 4; ++rt) {
        const int rl = rt * 16 + (lane & 15);
        const int sw = (rl & 7) << 4;
#pragma unroll
        for (int kt = 0; kt < 10; ++kt) {
            f32x4 lo, hi;
            if (kt < 8) {
                const char* buf = (kt < 4) ? bufA : bufB;
                int c0 = (kt & 3) * 128 + kg * 32;
                lo = *(const f32x4*)(buf + rl * 512 + (c0 ^ sw));
                hi = *(const f32x4*)(buf + rl * 512 + ((c0 + 16) ^ sw));
            } else {
                int c0 = (kt - 8) * 128 + kg * 32;
                lo = *(const f32x4*)(aux + rl * 176 + c0);
                hi = *(const f32x4*)(aux + rl * 176 + c0 + 16);
            }
            short8 afr;
            afr[0] = (short)f2bfbits(lo[0]); afr[1] = (short)f2bfbits(lo[1]);
            afr[2] = (short)f2bfbits(lo[2]); afr[3] = (short)f2bfbits(lo[3]);
            afr[4] = (short)f2bfbits(hi[0]); afr[5] = (short)f2bfbits(hi[1]);
            afr[6] = (short)f2bfbits(hi[2]); afr[7] = (short)f2bfbits(hi[3]);
            acc[rt] = __builtin_amdgcn_mfma_f32_16x16x32_bf16(afr, bq[kt], acc[rt], 0, 0, 0);
        }
    }

    __syncthreads();    // all waves done reading aux tail -> safe to reuse

    // epilogue: block transpose in aux -> coalesced 16B stores
    {
        unsigned short* st = (unsigned short*)aux;      // [64][64] u16 = 8 KB
        const int colb = wave * 16 + (lane & 15);
#pragma unroll
        for (int rt = 0; rt < 4; ++rt) {
            const int rbase = rt * 16 + (lane >> 4) * 4;
#pragma unroll
            for (int r = 0; r < 4; ++r)
                st[(rbase + r) * FOUT + colb] = f2bfbits(acc[rt][r]);
        }
        __syncthreads();
        const ushort8* sv = (const ushort8*)st;                 // 512 x 16B
        ushort8* hout = (ushort8*)(hb + (size_t)rowbase * FOUT);
        hout[threadIdx.x] = sv[threadIdx.x];
        hout[threadIdx.x + 256] = sv[threadIdx.x + 256];
    }
}

// ---------------------------------------------------------------------------
// Per-subgraph aggregate + norm + PReLU + pool + anchor (R13, unchanged).
// Thread t consumes chunk t's run for subgraph g (256 chunks, 256 threads).
// ---------------------------------------------------------------------------
__global__ __launch_bounds__(256) void agg_pool_kernel(const unsigned short* __restrict__ hb,
                                                       const unsigned short* __restrict__ bkt,
                                                       const unsigned* __restrict__ ofs,
                                                       const float* __restrict__ bias,
                                                       const float* __restrict__ prelu,
                                                       float* __restrict__ out) {
    __shared__ unsigned short hl[SSUB][FOUT];       // 16 KB bf16 bits
    __shared__ unsigned char  es[SSUB][64];         // 8 KB per-dst src lists
    __shared__ int   din[SSUB];
    __shared__ int   dout[SSUB];
    __shared__ float rout[SSUB];
    __shared__ float ps[4][FOUT];

    const int g = blockIdx.x;
    const int t = threadIdx.x;
    const int lane = t & 63;
    const int w = t >> 6;

    // load h tile (straight bf16 copy, 4 x ushort8 per thread)
    {
        const ushort8* hsrc = (const ushort8*)(hb + (size_t)g * SSUB * FOUT);
        ushort8* hdst = (ushort8*)&hl[0][0];
        for (int i = t; i < 1024; i += 256) hdst[i] = hsrc[i];
    }
    if (t < SSUB) { din[t] = 0; dout[t] = 0; }
    __syncthreads();

    // edge pass: thread t consumes chunk t's run for subgraph g
    {
        unsigned w32 = ofs[(size_t)t * BSUB + g];
        int st = (int)(w32 >> 16), cn = (int)(w32 & 0xffff);
        const unsigned short* ebb = bkt + ((size_t)t << 13) + st;
        for (int i = 0; i < cn; ++i) {
            unsigned e = ebb[i];
            int s = e >> 7, d = e & 127;
            int r = atomicAdd(&din[d], 1);
            es[d][r & 63] = (unsigned char)s;
            atomicAdd(&dout[s], 1);
        }
    }
    __syncthreads();
    if (t < SSUB) rout[t] = rsqrtf((float)max(dout[t], 1));
    __syncthreads();

    // register aggregation: wave w owns dst rows w, w+4, ...
    const float bv = bias[lane];
    const float a = prelu[0];
    float pool = 0.f;
#pragma unroll 4
    for (int ii = 0; ii < 32; ++ii) {
        int d = w + 4 * ii;
        int cd = min(din[d], 64);
        float accv = 0.f;
        const unsigned* ew = (const unsigned*)&es[d][0];
        int nw = (cd + 3) >> 2;
        for (int p = 0; p < nw; ++p) {
            unsigned wd = ew[p];                        // broadcast LDS read
            int rem = cd - p * 4;
#pragma unroll
            for (int b = 0; b < 4; ++b) {
                if (b < rem) {                          // wave-uniform predicate
                    int s = (wd >> (8 * b)) & 127;
                    accv += bf2f(hl[s][lane]) * rout[s];
                }
            }
        }
        float v = accv * rsqrtf((float)max(din[d], 1)) + bv;
        v = (v > 0.f) ? v : a * v;
        if (d == SSUB - 1)
            out[(size_t)(BSUB + g) * FOUT + lane] = v;  // anchor (wave 3)
        else
            pool += v;
    }
    ps[w][lane] = pool;
    __syncthreads();
    if (w == 0) {
        float s = (ps[0][lane] + ps[1][lane]) + (ps[2][lane] + ps[3][lane]);
        out[(size_t)g * FOUT + lane] = s * (1.0f / 127.0f);
    }
}

// ---------------------------------------------------------------------------
extern "C" void kernel_launch(void* const* d_in, const int* in_sizes, int n_in,
                              void* d_out, int out_size, void* d_ws, size_t ws_size,
                              hipStream_t stream) {
    const float* in_feat = (const float*)d_in[0];
    const float* W       = (const float*)d_in[1];
    const float* bias    = (const float*)d_in[2];
    const float* prelu   = (const float*)d_in[3];
    const int*   src     = (const int*)d_in[4];
    const int*   dst     = (const int*)d_in[5];
    float* out = (float*)d_out;

    char* ws = (char*)d_ws;
    short*          wfrag = (short*)(ws + 65536);                // 40 KB
    unsigned*       ofs   = (unsigned*)(ws + (2u << 20));        // 1 MB (256x1024 u32)
    unsigned short* bkt   = (unsigned short*)(ws + (4u << 20));  // 4 MB (256x8192 u16)
    unsigned short* hb    = (unsigned short*)(ws + (16u << 20)); // 16 MB bf16 h

    hipLaunchKernelGGL(bucket_prep_kernel, dim3(NCHUNK + 10), dim3(256), 0, stream,
                       src, dst, ofs, bkt, W, wfrag);
    hipLaunchKernelGGL(gemm_kernel,        dim3(NNODES/64),   dim3(256), 0, stream, in_feat, wfrag, hb);
    hipLaunchKernelGGL(agg_pool_kernel,    dim3(BSUB),        dim3(256), 0, stream, hb, bkt, ofs, bias, prelu, out);
}